// Round 2
// baseline (303.139 us; speedup 1.0000x reference)
//
#include <hip/hip_runtime.h>
#include <math.h>

// Tree message passing DP. B=64, C=2, L=4096, 4-ary tree: parent(j)=(j-1)>>2.
// messages[b,cs,j] = LSE_cp( emis[b,cp,p] + messages[b,cp,p] + T[j,p,cs,cp] )
// Depth <= 6; ancestor chain of j is pure index arithmetic, so each thread
// (b,j) recomputes its root->j chain. Two launches:
//   1) compact the 4095 used edges T[j,parent(j),:,:] into d_ws (64 KB)
//   2) straight-line 6-step chain, all loads unconditional & hoistable.

#define LL 4096
#define BB 64

__device__ __forceinline__ float lse2(float a, float b) {
    float hi = fmaxf(a, b);
    float lo = fminf(a, b);
    // exp(lo-hi) <= 1 -> log argument in [1,2]: well conditioned.
    return hi + __logf(1.0f + __expf(lo - hi));
}

// edge[j] = trans[j, (j-1)>>2, :, :]  (float4), edge[0] = 0
__global__ __launch_bounds__(256) void compact_edges(
    const float* __restrict__ trans, float4* __restrict__ edge)
{
    int j = blockIdx.x * 256 + threadIdx.x;   // 0..4095
    if (j == 0) { edge[0] = make_float4(0.f, 0.f, 0.f, 0.f); return; }
    int p = (j - 1) >> 2;
    edge[j] = *(const float4*)(trans + (((size_t)j * LL + p) << 2));
}

__global__ __launch_bounds__(256) void mp_chain_kernel(
    const float* __restrict__ emis,    // [B,2,L]
    const float4* __restrict__ edge,   // [L] compacted T[j,parent(j)]
    float* __restrict__ out)           // [B,2,L]
{
    int tid = blockIdx.x * blockDim.x + threadIdx.x;  // 0..B*L-1
    int b = tid >> 12;
    int j = tid & (LL - 1);
    const float* eb = emis + (size_t)b * 2 * LL;

    // level of j: level starts S[k] = (4^k-1)/3 = 0x5555... & ((1<<2k)-1)
    int l = (j >= 1) + (j >= 5) + (j >= 21) + (j >= 85) + (j >= 341) + (j >= 1365);
    unsigned Sl = 0x55555555u & ((1u << (2 * l)) - 1u);
    int o = j - (int)Sl;          // offset within level l
    int shift = 6 - l;            // steps s=1..shift are inactive (pad at front)

    float m0 = 0.f, m1 = 0.f;
    int prev = 0;
#pragma unroll
    for (int s = 1; s <= 6; ++s) {
        bool active = (s > shift);
        int k = s - shift; if (k < 1) k = 1;               // clamp (unused if !active)
        unsigned Sk = 0x55555555u & ((1u << (2 * k)) - 1u);
        // ancestor of j at level k; when active, l-k == 6-s (compile-time shift)
        int cur = active ? (int)(Sk + (unsigned)(o >> (2 * (6 - s)))) : 0;
        float4 t = edge[cur];                               // coalesced/broadcast
        float e0 = eb[prev];                                // local[b, cp=0] at prev
        float e1 = eb[LL + prev];                           // local[b, cp=1]
        float l0 = e0 + m0, l1 = e1 + m1;
        float n0 = lse2(l0 + t.x, l1 + t.y);                // cs = 0
        float n1 = lse2(l0 + t.z, l1 + t.w);                // cs = 1
        m0 = active ? n0 : m0;
        m1 = active ? n1 : m1;
        prev = cur;
    }

    out[(size_t)b * 2 * LL + j]      = m0;   // messages[b,0,j]
    out[(size_t)b * 2 * LL + LL + j] = m1;   // messages[b,1,j]
}

extern "C" void kernel_launch(void* const* d_in, const int* in_sizes, int n_in,
                              void* d_out, int out_size, void* d_ws, size_t ws_size,
                              hipStream_t stream) {
    const float* emis  = (const float*)d_in[0];   // [64,2,4096] fp32
    const float* trans = (const float*)d_in[1];   // [4096,4096,2,2] fp32
    float* out = (float*)d_out;                   // [64,2,4096] fp32
    float4* edge = (float4*)d_ws;                 // 4096 * 16 B = 64 KB scratch

    compact_edges<<<LL / 256, 256, 0, stream>>>(trans, edge);
    mp_chain_kernel<<<(BB * LL) / 256, 256, 0, stream>>>(emis, edge, out);
}